// Round 7
// baseline (680.788 us; speedup 1.0000x reference)
//
#include <hip/hip_runtime.h>
#include <hip/hip_bf16.h>

#define N_NODES 50000
#define N_EDGES 1600000
#define CH 512
#define NB 25                      // col buckets of 2048 (50000/2048 -> 0..24)
#define N_KEYS (N_NODES * NB)      // 1,250,000
#define BS_ELEMS 4096              // elements per scan block (256 thr x 16)
#define NBLK ((N_KEYS + BS_ELEMS - 1) / BS_ELEMS)  // 306

typedef short short8v __attribute__((ext_vector_type(8)));
typedef float f32x4 __attribute__((ext_vector_type(4)));
typedef unsigned short ushort8v __attribute__((ext_vector_type(8)));
typedef _Float16 half8v __attribute__((ext_vector_type(8)));
typedef int int2v __attribute__((ext_vector_type(2)));      // native vec for nt builtins
typedef float float4v __attribute__((ext_vector_type(4)));  // native vec for nt builtins

#define GLOAD_LDS16(gptr, lptr)                                                        \
    __builtin_amdgcn_global_load_lds((const __attribute__((address_space(1))) void*)(gptr), \
                                     (__attribute__((address_space(3))) void*)(lptr), 16, 0, 0)

// round-to-nearest-even fp32 -> bf16 bits (finite inputs)
__device__ inline unsigned short f2bf(float x) {
    unsigned u = __float_as_uint(x);
    u = (u + 0x7FFF + ((u >> 16) & 1)) >> 16;
    return (unsigned short)u;
}
__device__ inline float bf2f(unsigned short b) {
    return __uint_as_float(((unsigned)b) << 16);
}
__device__ inline unsigned short f2h(float x) {
    union { _Float16 h; unsigned short u; } cv;
    cv.h = (_Float16)x;   // v_cvt_f16_f32, RNE
    return cv.u;
}

// ---------------- edge bucketing: counting sort by key = row*NB + (col>>11) ----------------

__global__ __launch_bounds__(256) void hist_kernel(const int* __restrict__ row,
                                                   const int* __restrict__ col,
                                                   int* __restrict__ counts) {
    int e = blockIdx.x * 256 + threadIdx.x;
    if (e < N_EDGES) {
        int key = row[e] * NB + (col[e] >> 11);
        atomicAdd(&counts[key], 1);
    }
}

// per-block sums over BS_ELEMS
__global__ __launch_bounds__(256) void bsum_kernel(const int* __restrict__ counts,
                                                   int* __restrict__ bsum) {
    __shared__ int red[256];
    const int t = threadIdx.x;
    const int base = blockIdx.x * BS_ELEMS + t * 16;
    int s = 0;
#pragma unroll
    for (int q = 0; q < 16; ++q) {
        int i = base + q;
        if (i < N_KEYS) s += counts[i];
    }
    red[t] = s;
    __syncthreads();
    for (int st = 128; st > 0; st >>= 1) {
        if (t < st) red[t] += red[t + st];
        __syncthreads();
    }
    if (t == 0) bsum[blockIdx.x] = red[0];
}

// exclusive scan of NBLK (<=512) block sums, single block, 2 elems/thread
__global__ __launch_bounds__(256) void bscan_kernel(const int* __restrict__ bsum,
                                                    int* __restrict__ bbase) {
    __shared__ int sc[256];
    const int t = threadIdx.x;
    int a0 = (2 * t < NBLK) ? bsum[2 * t] : 0;
    int a1 = (2 * t + 1 < NBLK) ? bsum[2 * t + 1] : 0;
    int v = a0 + a1;
    sc[t] = v;
    __syncthreads();
    for (int d = 1; d < 256; d <<= 1) {
        int a = (t >= d) ? sc[t - d] : 0;
        __syncthreads();
        sc[t] += a;
        __syncthreads();
    }
    int ex = sc[t] - v;
    if (2 * t < NBLK) bbase[2 * t] = ex;
    if (2 * t + 1 < NBLK) bbase[2 * t + 1] = ex + a0;
}

// rescan: keyoff[i] = global exclusive prefix; nxt[i] = same
__global__ __launch_bounds__(256) void offsets_kernel(const int* __restrict__ counts,
                                                      const int* __restrict__ bbase,
                                                      int* __restrict__ keyoff,
                                                      int* __restrict__ nxt) {
    __shared__ int sc[256];
    const int t = threadIdx.x;
    const int base = blockIdx.x * BS_ELEMS + t * 16;
    int vals[16];
    int s = 0;
#pragma unroll
    for (int q = 0; q < 16; ++q) {
        int i = base + q;
        vals[q] = (i < N_KEYS) ? counts[i] : 0;
        s += vals[q];
    }
    sc[t] = s;
    __syncthreads();
    for (int d = 1; d < 256; d <<= 1) {
        int a = (t >= d) ? sc[t - d] : 0;
        __syncthreads();
        sc[t] += a;
        __syncthreads();
    }
    int run = bbase[blockIdx.x] + sc[t] - s;
#pragma unroll
    for (int q = 0; q < 16; ++q) {
        int i = base + q;
        if (i < N_KEYS) { keyoff[i] = run; nxt[i] = run; }
        run += vals[q];
    }
    if (blockIdx.x == 0 && t == 0) keyoff[N_KEYS] = N_EDGES;
}

__global__ __launch_bounds__(256) void scatter_kernel(const int* __restrict__ row,
                                                      const int* __restrict__ col,
                                                      const float* __restrict__ val,
                                                      int* __restrict__ nxt,
                                                      int2* __restrict__ ep) {
    int e = blockIdx.x * 256 + threadIdx.x;
    if (e < N_EDGES) {
        int c = col[e];
        int key = row[e] * NB + (c >> 11);
        int p = atomicAdd(&nxt[key], 1);
        ep[p] = make_int2(c, __float_as_int(val[e]));
    }
}

// ---------------- W pre-transform: Wc[kt][n][64] bf16 (hi k0..31 | lo k0..31) ----------------

__global__ __launch_bounds__(256) void prep_w(const float* __restrict__ W,
                                              unsigned short* __restrict__ Wc) {
    __shared__ float tile[32][65];
    const int kt = blockIdx.x;       // 16 K-tiles of 32
    const int nb = blockIdx.y * 64;  // 8 col groups of 64
    const int t = threadIdx.x;
    const int nl = t & 63, kl = t >> 6;
#pragma unroll
    for (int p = 0; p < 8; ++p) {
        int k = p * 4 + kl;
        tile[k][nl] = W[(size_t)(kt * 32 + k) * CH + nb + nl];
    }
    __syncthreads();
    const int n_local = t >> 2, j = t & 3;
    ushort8v hi, lo;
#pragma unroll
    for (int q = 0; q < 8; ++q) {
        float x = tile[j * 8 + q][n_local];
        unsigned short h = f2bf(x);
        hi[q] = h;
        lo[q] = f2bf(x - bf2f(h));
    }
    size_t base = ((size_t)kt * 512 + nb + n_local) * 64 + j * 8;
    *(ushort8v*)&Wc[base] = hi;       // hi slot j
    *(ushort8v*)&Wc[base + 32] = lo;  // lo slot 4+j
}

// ---------------- GEMM: support(fp16) = X @ W via bf16x3 MFMA ----------------
// BM=BN=128, BK=32, 256 threads (4 waves 2x2, 64x64 each).
// LDS rows = 128B (32 hi bf16 | 32 lo bf16), 16B slots XOR-swizzled: slot' = slot ^ (row&7).

__global__ __launch_bounds__(256) void gemm_kernel(const float* __restrict__ X,
                                                   const unsigned short* __restrict__ Wc,
                                                   unsigned short* __restrict__ S) {
    __shared__ __align__(16) unsigned short Al[128 * 64];
    __shared__ __align__(16) unsigned short Bl[128 * 64];

    const int tid = threadIdx.x;
    const int wave = tid >> 6;
    const int lane = tid & 63;
    const int wm = (wave >> 1) * 64;
    const int wn = (wave & 1) * 64;
    const int m0 = blockIdx.x * 128;
    const int n0 = blockIdx.y * 128;

    // B staging lane-constant source offset (ushort units): row 64, slot 8
    const int lrow = lane >> 3, lslot = lane & 7;
    const int b_lane_off = lrow * 64 + ((lslot ^ lrow) << 3);

    // A staging: thread -> (row, k-half)
    const int srow = tid >> 1;
    const int skh = tid & 1;
    const int gm_s = m0 + srow;
    const int r7 = srow & 7;

    f32x4 acc[4][4] = {};

    for (int kt = 0; kt < 16; ++kt) {
        // ---- B: async global->LDS, pre-swizzled source, linear dest ----
        const unsigned short* bsrc = Wc + ((size_t)kt * 512 + n0 + wave * 32) * 64 + b_lane_off;
        unsigned short* bdst = &Bl[(wave * 32) * 64];
        GLOAD_LDS16(bsrc, bdst);
        GLOAD_LDS16(bsrc + 512, bdst + 512);
        GLOAD_LDS16(bsrc + 1024, bdst + 1024);
        GLOAD_LDS16(bsrc + 1536, bdst + 1536);

        // ---- A: reg-stage fp32 -> bf16 hi/lo, swizzled ds_write ----
        float xv[16];
        if (gm_s < N_NODES) {
            const float* xp = &X[(size_t)gm_s * CH + kt * 32 + skh * 16];
            *(float4*)&xv[0]  = *(const float4*)&xp[0];
            *(float4*)&xv[4]  = *(const float4*)&xp[4];
            *(float4*)&xv[8]  = *(const float4*)&xp[8];
            *(float4*)&xv[12] = *(const float4*)&xp[12];
        } else {
#pragma unroll
            for (int q = 0; q < 16; ++q) xv[q] = 0.f;
        }
        ushort8v h0, h1, l0, l1;
#pragma unroll
        for (int q = 0; q < 8; ++q) {
            unsigned short h = f2bf(xv[q]);
            h0[q] = h;
            l0[q] = f2bf(xv[q] - bf2f(h));
            unsigned short h2 = f2bf(xv[8 + q]);
            h1[q] = h2;
            l1[q] = f2bf(xv[8 + q] - bf2f(h2));
        }
        {
            const int s0 = skh * 2, s1 = skh * 2 + 1;
            unsigned short* arow = &Al[srow * 64];
            *(ushort8v*)&arow[((s0 ^ r7) << 3)] = h0;
            *(ushort8v*)&arow[((s1 ^ r7) << 3)] = h1;
            *(ushort8v*)&arow[(((s0 | 4) ^ r7) << 3)] = l0;
            *(ushort8v*)&arow[(((s1 | 4) ^ r7) << 3)] = l1;
        }
        __syncthreads();

        // ---- fragments + 48 MFMA ----
        const int fr = lane & 15;
        const int fs = lane >> 4;
        const int fx = lane & 7;
        short8v ahi[4], alo[4];
#pragma unroll
        for (int mi = 0; mi < 4; ++mi) {
            const unsigned short* ar = &Al[(wm + mi * 16 + fr) * 64];
            ahi[mi] = *(const short8v*)&ar[((fs ^ fx) << 3)];
            alo[mi] = *(const short8v*)&ar[(((fs | 4) ^ fx) << 3)];
        }
#pragma unroll
        for (int ni = 0; ni < 4; ++ni) {
            const unsigned short* br = &Bl[(wn + ni * 16 + fr) * 64];
            short8v bhi = *(const short8v*)&br[((fs ^ fx) << 3)];
            short8v blo = *(const short8v*)&br[(((fs | 4) ^ fx) << 3)];
#pragma unroll
            for (int mi = 0; mi < 4; ++mi) {
                acc[mi][ni] = __builtin_amdgcn_mfma_f32_16x16x32_bf16(ahi[mi], bhi, acc[mi][ni], 0, 0, 0);
                acc[mi][ni] = __builtin_amdgcn_mfma_f32_16x16x32_bf16(ahi[mi], blo, acc[mi][ni], 0, 0, 0);
                acc[mi][ni] = __builtin_amdgcn_mfma_f32_16x16x32_bf16(alo[mi], bhi, acc[mi][ni], 0, 0, 0);
            }
        }
        __syncthreads();
    }

    // ---- store C as fp16: col = lane&15, row = (lane>>4)*4 + reg ----
    const int crow = (lane >> 4) * 4;
    const int ccol = lane & 15;
#pragma unroll
    for (int mi = 0; mi < 4; ++mi) {
#pragma unroll
        for (int r = 0; r < 4; ++r) {
            int gm = m0 + wm + mi * 16 + crow + r;
            if (gm < N_NODES) {
#pragma unroll
                for (int ni = 0; ni < 4; ++ni) {
                    S[(size_t)gm * CH + n0 + wn + ni * 16 + ccol] = f2h(acc[mi][ni][r]);
                }
            }
        }
    }
}

// ---------------- SpMM: out[r] = sum_e val_e * support[col_e] ----------------
// one wave per row; lane covers 8 channels (half8 = 16B/lane); 4x edge unroll.
// nt hints: ep stream and out store bypass/deprioritize L2 so support gathers stay cached.

__global__ __launch_bounds__(128) void spmm_kernel(const int* __restrict__ keyoff,
                                                   const int2v* __restrict__ ep,
                                                   const unsigned short* __restrict__ S,
                                                   float* __restrict__ out) {
    const int r = blockIdx.x * 2 + (threadIdx.x >> 6);
    const int lane = threadIdx.x & 63;
    const int c = lane * 8;
    const int start = keyoff[r * NB];
    const int end = keyoff[(r + 1) * NB];

    float acc[8] = {0.f, 0.f, 0.f, 0.f, 0.f, 0.f, 0.f, 0.f};
    int e = start;
    for (; e + 3 < end; e += 4) {
        const int2v e0 = __builtin_nontemporal_load(&ep[e]);
        const int2v e1 = __builtin_nontemporal_load(&ep[e + 1]);
        const int2v e2 = __builtin_nontemporal_load(&ep[e + 2]);
        const int2v e3 = __builtin_nontemporal_load(&ep[e + 3]);
        const half8v s0 = *(const half8v*)&S[(size_t)e0.x * CH + c];
        const half8v s1 = *(const half8v*)&S[(size_t)e1.x * CH + c];
        const half8v s2 = *(const half8v*)&S[(size_t)e2.x * CH + c];
        const half8v s3 = *(const half8v*)&S[(size_t)e3.x * CH + c];
        const float v0 = __int_as_float(e0.y);
        const float v1 = __int_as_float(e1.y);
        const float v2 = __int_as_float(e2.y);
        const float v3 = __int_as_float(e3.y);
#pragma unroll
        for (int j = 0; j < 8; ++j) {
            acc[j] += v0 * (float)s0[j];
            acc[j] += v1 * (float)s1[j];
            acc[j] += v2 * (float)s2[j];
            acc[j] += v3 * (float)s3[j];
        }
    }
    for (; e < end; ++e) {
        const int2v e0 = __builtin_nontemporal_load(&ep[e]);
        const half8v s0 = *(const half8v*)&S[(size_t)e0.x * CH + c];
        const float v0 = __int_as_float(e0.y);
#pragma unroll
        for (int j = 0; j < 8; ++j) acc[j] += v0 * (float)s0[j];
    }
    float4v o0 = {acc[0], acc[1], acc[2], acc[3]};
    float4v o1 = {acc[4], acc[5], acc[6], acc[7]};
    __builtin_nontemporal_store(o0, (float4v*)&out[(size_t)r * CH + c]);
    __builtin_nontemporal_store(o1, (float4v*)&out[(size_t)r * CH + c + 4]);
}

// ---------------- launch ----------------

extern "C" void kernel_launch(void* const* d_in, const int* in_sizes, int n_in,
                              void* d_out, int out_size, void* d_ws, size_t ws_size,
                              hipStream_t stream) {
    const float* x        = (const float*)d_in[0];
    const float* adj_vals = (const float*)d_in[1];
    const int*   edge_row = (const int*)d_in[2];
    const int*   edge_col = (const int*)d_in[3];
    const float* weight   = (const float*)d_in[4];
    float* out = (float*)d_out;

    auto align256 = [](size_t v) { return (v + 255) & ~(size_t)255; };
    char* ws = (char*)d_ws;
    size_t off = 0;
    unsigned short* support = (unsigned short*)(ws + off); off = align256(off + (size_t)N_NODES * CH * sizeof(unsigned short));
    int*   counts  = (int*)(ws + off);            off = align256(off + (size_t)N_KEYS * sizeof(int));
    int*   keyoff  = (int*)(ws + off);            off = align256(off + (size_t)(N_KEYS + 1) * sizeof(int));
    int*   nxt     = (int*)(ws + off);            off = align256(off + (size_t)N_KEYS * sizeof(int));
    int2*  ep      = (int2*)(ws + off);           off = align256(off + (size_t)N_EDGES * sizeof(int2));
    unsigned short* Wc = (unsigned short*)(ws + off); off = align256(off + (size_t)16 * 512 * 64 * sizeof(unsigned short));
    int*   bsum    = (int*)(ws + off);            off = align256(off + (size_t)NBLK * sizeof(int));
    int*   bbase   = (int*)(ws + off);            off = align256(off + (size_t)NBLK * sizeof(int));

    (void)hipMemsetAsync(counts, 0, (size_t)N_KEYS * sizeof(int), stream);

    const int EB = (N_EDGES + 255) / 256;
    hist_kernel<<<EB, 256, 0, stream>>>(edge_row, edge_col, counts);
    bsum_kernel<<<NBLK, 256, 0, stream>>>(counts, bsum);
    bscan_kernel<<<1, 256, 0, stream>>>(bsum, bbase);
    offsets_kernel<<<NBLK, 256, 0, stream>>>(counts, bbase, keyoff, nxt);
    scatter_kernel<<<EB, 256, 0, stream>>>(edge_row, edge_col, adj_vals, nxt, ep);

    dim3 wgrid(16, 8);
    prep_w<<<wgrid, 256, 0, stream>>>(weight, Wc);

    dim3 ggrid((N_NODES + 127) / 128, CH / 128);
    gemm_kernel<<<ggrid, 256, 0, stream>>>(x, Wc, support);

    spmm_kernel<<<N_NODES / 2, 128, 0, stream>>>(keyoff, (const int2v*)ep, support, out);
}

// Round 8
// 675.836 us; speedup vs baseline: 1.0073x; 1.0073x over previous
//
#include <hip/hip_runtime.h>
#include <hip/hip_bf16.h>

#define N_NODES 50000
#define N_EDGES 1600000
#define CH 512
#define M_PAD 50048                // 391 * 128
#define SCAN_B 196                 // ceil(50000/256)

typedef float f32x4 __attribute__((ext_vector_type(4)));
typedef unsigned short ushort8v __attribute__((ext_vector_type(8)));
typedef _Float16 half8v __attribute__((ext_vector_type(8)));

#define GLOAD_LDS16(gptr, lptr)                                                        \
    __builtin_amdgcn_global_load_lds((const __attribute__((address_space(1))) void*)(gptr), \
                                     (__attribute__((address_space(3))) void*)(lptr), 16, 0, 0)

__device__ inline unsigned short f2h(float x) {
    union { _Float16 h; unsigned short u; } cv;
    cv.h = (_Float16)x;   // v_cvt_f16_f32, RNE
    return cv.u;
}
__device__ inline float h2f(unsigned short u) {
    union { unsigned short u; _Float16 h; } cv;
    cv.u = u;
    return (float)cv.h;
}

// ---------------- edge bucketing (counting sort by row) ----------------

__global__ __launch_bounds__(256) void hist_kernel(const int* __restrict__ row,
                                                   int* __restrict__ counts) {
    int e = blockIdx.x * 256 + threadIdx.x;
    if (e < N_EDGES) atomicAdd(&counts[row[e]], 1);
}

__global__ __launch_bounds__(256) void bsum_kernel(const int* __restrict__ counts,
                                                   int* __restrict__ bsum) {
    __shared__ int red[256];
    int i = blockIdx.x * 256 + threadIdx.x;
    red[threadIdx.x] = (i < N_NODES) ? counts[i] : 0;
    __syncthreads();
    for (int s = 128; s > 0; s >>= 1) {
        if (threadIdx.x < s) red[threadIdx.x] += red[threadIdx.x + s];
        __syncthreads();
    }
    if (threadIdx.x == 0) bsum[blockIdx.x] = red[0];
}

__global__ __launch_bounds__(256) void bscan_kernel(const int* __restrict__ bsum,
                                                    int* __restrict__ bbase) {
    __shared__ int sc[256];
    int t = threadIdx.x;
    int v = (t < SCAN_B) ? bsum[t] : 0;
    sc[t] = v;
    __syncthreads();
    for (int d = 1; d < 256; d <<= 1) {
        int a = (t >= d) ? sc[t - d] : 0;
        __syncthreads();
        sc[t] += a;
        __syncthreads();
    }
    if (t < SCAN_B) bbase[t] = sc[t] - v;  // exclusive
}

__global__ __launch_bounds__(256) void offsets_kernel(const int* __restrict__ counts,
                                                      const int* __restrict__ bbase,
                                                      int* __restrict__ offsets,
                                                      int* __restrict__ nxt) {
    __shared__ int sc[256];
    int t = threadIdx.x;
    int i = blockIdx.x * 256 + t;
    int v = (i < N_NODES) ? counts[i] : 0;
    sc[t] = v;
    __syncthreads();
    for (int d = 1; d < 256; d <<= 1) {
        int a = (t >= d) ? sc[t - d] : 0;
        __syncthreads();
        sc[t] += a;
        __syncthreads();
    }
    int off = bbase[blockIdx.x] + sc[t] - v;
    if (i < N_NODES) { offsets[i] = off; nxt[i] = off; }
    if (i == 0) offsets[N_NODES] = N_EDGES;
}

__global__ __launch_bounds__(256) void scatter_kernel(const int* __restrict__ row,
                                                      const int* __restrict__ col,
                                                      const float* __restrict__ val,
                                                      int* __restrict__ nxt,
                                                      int2* __restrict__ ep) {
    int e = blockIdx.x * 256 + threadIdx.x;
    if (e < N_EDGES) {
        int r = row[e];
        int p = atomicAdd(&nxt[r], 1);
        ep[p] = make_int2(col[e], __float_as_int(val[e]));
    }
}

// ---------------- X pre-convert: Xa[kt][m][32] fp16 (plain slot order) ----------------
// gemm pre-swizzles the global source address, so Xa stores natural order.

__global__ __launch_bounds__(256) void prep_x(const float* __restrict__ X,
                                              unsigned short* __restrict__ Xa) {
    const int t = threadIdx.x;
    const int m = blockIdx.x * 32 + (t >> 3);
    const int cpart = t & 7;  // 64-ch chunk -> kts cpart*2, cpart*2+1
    float xv[64];
    if (m < N_NODES) {
        const float* xp = &X[(size_t)m * CH + cpart * 64];
#pragma unroll
        for (int i = 0; i < 16; ++i)
            *(float4*)&xv[i * 4] = *(const float4*)&xp[i * 4];
    } else {
#pragma unroll
        for (int i = 0; i < 64; ++i) xv[i] = 0.f;
    }
#pragma unroll
    for (int kk = 0; kk < 2; ++kk) {
        const int kt = cpart * 2 + kk;
        ushort8v o[4];
#pragma unroll
        for (int q = 0; q < 32; ++q)
            o[q >> 3][q & 7] = f2h(xv[kk * 32 + q]);
        unsigned short* dst = &Xa[((size_t)kt * M_PAD + m) * 32];
        *(ushort8v*)&dst[0]  = o[0];
        *(ushort8v*)&dst[8]  = o[1];
        *(ushort8v*)&dst[16] = o[2];
        *(ushort8v*)&dst[24] = o[3];
    }
}

// ---------------- W pre-transform: Wb[kt][n][64] fp16 (hi k0..31 | lo k0..31) ----------------

__global__ __launch_bounds__(256) void prep_w(const float* __restrict__ W,
                                              unsigned short* __restrict__ Wb) {
    __shared__ float tile[32][65];
    const int kt = blockIdx.x;       // 16 K-tiles of 32
    const int nb = blockIdx.y * 64;  // 8 col groups of 64
    const int t = threadIdx.x;
    const int nl = t & 63, kl = t >> 6;
#pragma unroll
    for (int p = 0; p < 8; ++p) {
        int k = p * 4 + kl;
        tile[k][nl] = W[(size_t)(kt * 32 + k) * CH + nb + nl];
    }
    __syncthreads();
    const int n_local = t >> 2, j = t & 3;
    ushort8v hi, lo;
#pragma unroll
    for (int q = 0; q < 8; ++q) {
        float x = tile[j * 8 + q][n_local];
        unsigned short h = f2h(x);
        hi[q] = h;
        lo[q] = f2h(x - h2f(h));
    }
    size_t base = ((size_t)kt * 512 + nb + n_local) * 64 + j * 8;
    *(ushort8v*)&Wb[base] = hi;       // hi slot j
    *(ushort8v*)&Wb[base + 32] = lo;  // lo slot 4+j
}

// ---------------- GEMM: support(fp16) = Xa @ (Whi + Wlo) via fp16 MFMA x2 ----------------
// BM=BN=128, BK=32, 256 threads (4 waves 2x2, 64x64 each). All staging via global_load_lds.
// Bl rows 128B, 16B slots XOR-swizzled by row&7; Al rows 64B, slots XOR-swizzled by row&3.

__global__ __launch_bounds__(256) void gemm_kernel(const unsigned short* __restrict__ Xa,
                                                   const unsigned short* __restrict__ Wb,
                                                   unsigned short* __restrict__ S) {
    __shared__ __align__(16) unsigned short Al[128 * 32];
    __shared__ __align__(16) unsigned short Bl[128 * 64];

    const int tid = threadIdx.x;
    const int wave = tid >> 6;
    const int lane = tid & 63;
    const int wm = (wave >> 1) * 64;
    const int wn = (wave & 1) * 64;
    const int m0 = blockIdx.x * 128;
    const int n0 = blockIdx.y * 128;

    // B staging lane offset (elems): 8 rows of 64, slot pre-swizzled by row&7
    const int lrow = lane >> 3, lslot = lane & 7;
    const int b_lane_off = lrow * 64 + ((lslot ^ lrow) << 3);
    // A staging lane offset (elems): 16 rows of 32, slot pre-swizzled by row&3
    const int arow_l = lane >> 2, aslot = lane & 3;
    const int a_lane_off = arow_l * 32 + ((aslot ^ (arow_l & 3)) << 3);

    const int fr = lane & 15;
    const int fs = lane >> 4;
    const int fx3 = fr & 3;
    const int fx7 = fr & 7;

    f32x4 acc[4][4] = {};

    for (int kt = 0; kt < 16; ++kt) {
        // ---- B: 4 waves x 4 calls -> 128 rows x 64 ----
        const unsigned short* bsrc = Wb + ((size_t)kt * 512 + n0 + wave * 32) * 64 + b_lane_off;
        unsigned short* bdst = &Bl[(wave * 32) * 64];
        GLOAD_LDS16(bsrc, bdst);
        GLOAD_LDS16(bsrc + 512, bdst + 512);
        GLOAD_LDS16(bsrc + 1024, bdst + 1024);
        GLOAD_LDS16(bsrc + 1536, bdst + 1536);

        // ---- A: 4 waves x 2 calls -> 128 rows x 32 ----
        const unsigned short* asrc = Xa + ((size_t)kt * M_PAD + m0 + wave * 16) * 32 + a_lane_off;
        unsigned short* adst = &Al[(wave * 16) * 32];
        GLOAD_LDS16(asrc, adst);
        GLOAD_LDS16(asrc + 64 * 32, adst + 64 * 32);

        __syncthreads();

        // ---- fragments + 32 MFMA ----
        half8v af[4];
#pragma unroll
        for (int mi = 0; mi < 4; ++mi)
            af[mi] = *(const half8v*)&Al[(wm + mi * 16 + fr) * 32 + ((fs ^ fx3) << 3)];
#pragma unroll
        for (int ni = 0; ni < 4; ++ni) {
            const unsigned short* br = &Bl[(wn + ni * 16 + fr) * 64];
            half8v bhi = *(const half8v*)&br[((fs ^ fx7) << 3)];
            half8v blo = *(const half8v*)&br[(((fs | 4) ^ fx7) << 3)];
#pragma unroll
            for (int mi = 0; mi < 4; ++mi) {
                acc[mi][ni] = __builtin_amdgcn_mfma_f32_16x16x32_f16(af[mi], bhi, acc[mi][ni], 0, 0, 0);
                acc[mi][ni] = __builtin_amdgcn_mfma_f32_16x16x32_f16(af[mi], blo, acc[mi][ni], 0, 0, 0);
            }
        }
        __syncthreads();
    }

    // ---- store C as fp16: col = lane&15, row = (lane>>4)*4 + reg ----
    const int crow = (lane >> 4) * 4;
    const int ccol = lane & 15;
#pragma unroll
    for (int mi = 0; mi < 4; ++mi) {
#pragma unroll
        for (int r = 0; r < 4; ++r) {
            int gm = m0 + wm + mi * 16 + crow + r;
            if (gm < N_NODES) {
#pragma unroll
                for (int ni = 0; ni < 4; ++ni) {
                    S[(size_t)gm * CH + n0 + wn + ni * 16 + ccol] = f2h(acc[mi][ni][r]);
                }
            }
        }
    }
}

// ---------------- SpMM: out[r] = sum_e val_e * support[col_e] ----------------
// one wave per row; lane covers 8 channels (half8 = 16B/lane); 4x edge unroll. (R4-proven)

__global__ __launch_bounds__(128) void spmm_kernel(const int* __restrict__ offsets,
                                                   const int2* __restrict__ ep,
                                                   const unsigned short* __restrict__ S,
                                                   float* __restrict__ out) {
    const int r = blockIdx.x * 2 + (threadIdx.x >> 6);
    const int lane = threadIdx.x & 63;
    const int c = lane * 8;
    const int start = offsets[r];
    const int end = offsets[r + 1];

    float acc[8] = {0.f, 0.f, 0.f, 0.f, 0.f, 0.f, 0.f, 0.f};
    int e = start;
    for (; e + 3 < end; e += 4) {
        const int2 e0 = ep[e];
        const int2 e1 = ep[e + 1];
        const int2 e2 = ep[e + 2];
        const int2 e3 = ep[e + 3];
        const half8v s0 = *(const half8v*)&S[(size_t)e0.x * CH + c];
        const half8v s1 = *(const half8v*)&S[(size_t)e1.x * CH + c];
        const half8v s2 = *(const half8v*)&S[(size_t)e2.x * CH + c];
        const half8v s3 = *(const half8v*)&S[(size_t)e3.x * CH + c];
        const float v0 = __int_as_float(e0.y);
        const float v1 = __int_as_float(e1.y);
        const float v2 = __int_as_float(e2.y);
        const float v3 = __int_as_float(e3.y);
#pragma unroll
        for (int j = 0; j < 8; ++j) {
            acc[j] += v0 * (float)s0[j];
            acc[j] += v1 * (float)s1[j];
            acc[j] += v2 * (float)s2[j];
            acc[j] += v3 * (float)s3[j];
        }
    }
    for (; e < end; ++e) {
        const int2 e0 = ep[e];
        const half8v s0 = *(const half8v*)&S[(size_t)e0.x * CH + c];
        const float v0 = __int_as_float(e0.y);
#pragma unroll
        for (int j = 0; j < 8; ++j) acc[j] += v0 * (float)s0[j];
    }
    float4 o0 = {acc[0], acc[1], acc[2], acc[3]};
    float4 o1 = {acc[4], acc[5], acc[6], acc[7]};
    *(float4*)&out[(size_t)r * CH + c] = o0;
    *(float4*)&out[(size_t)r * CH + c + 4] = o1;
}

// ---------------- launch ----------------

extern "C" void kernel_launch(void* const* d_in, const int* in_sizes, int n_in,
                              void* d_out, int out_size, void* d_ws, size_t ws_size,
                              hipStream_t stream) {
    const float* x        = (const float*)d_in[0];
    const float* adj_vals = (const float*)d_in[1];
    const int*   edge_row = (const int*)d_in[2];
    const int*   edge_col = (const int*)d_in[3];
    const float* weight   = (const float*)d_in[4];
    float* out = (float*)d_out;

    auto align256 = [](size_t v) { return (v + 255) & ~(size_t)255; };
    char* ws = (char*)d_ws;
    size_t off = 0;
    unsigned short* support = (unsigned short*)(ws + off); off = align256(off + (size_t)N_NODES * CH * sizeof(unsigned short));
    unsigned short* Xa = (unsigned short*)(ws + off);      off = align256(off + (size_t)16 * M_PAD * 32 * sizeof(unsigned short));
    int*   counts  = (int*)(ws + off);            off = align256(off + (size_t)N_NODES * sizeof(int));
    int*   offsets = (int*)(ws + off);            off = align256(off + (size_t)(N_NODES + 1) * sizeof(int));
    int*   nxt     = (int*)(ws + off);            off = align256(off + (size_t)N_NODES * sizeof(int));
    int2*  ep      = (int2*)(ws + off);           off = align256(off + (size_t)N_EDGES * sizeof(int2));
    unsigned short* Wb = (unsigned short*)(ws + off); off = align256(off + (size_t)16 * 512 * 64 * sizeof(unsigned short));
    int*   bsum    = (int*)(ws + off);            off = align256(off + (size_t)SCAN_B * sizeof(int));
    int*   bbase   = (int*)(ws + off);            off = align256(off + (size_t)SCAN_B * sizeof(int));

    (void)hipMemsetAsync(counts, 0, (size_t)N_NODES * sizeof(int), stream);

    const int EB = (N_EDGES + 255) / 256;
    hist_kernel<<<EB, 256, 0, stream>>>(edge_row, counts);
    bsum_kernel<<<SCAN_B, 256, 0, stream>>>(counts, bsum);
    bscan_kernel<<<1, 256, 0, stream>>>(bsum, bbase);
    offsets_kernel<<<SCAN_B, 256, 0, stream>>>(counts, bbase, offsets, nxt);
    scatter_kernel<<<EB, 256, 0, stream>>>(edge_row, edge_col, adj_vals, nxt, ep);

    prep_x<<<M_PAD / 32, 256, 0, stream>>>(x, Xa);
    dim3 wgrid(16, 8);
    prep_w<<<wgrid, 256, 0, stream>>>(weight, Wb);

    dim3 ggrid(M_PAD / 128, CH / 128);
    gemm_kernel<<<ggrid, 256, 0, stream>>>(Xa, Wb, support);

    spmm_kernel<<<N_NODES / 2, 128, 0, stream>>>(offsets, ep, support, out);
}

// Round 9
// 666.544 us; speedup vs baseline: 1.0214x; 1.0139x over previous
//
#include <hip/hip_runtime.h>
#include <hip/hip_bf16.h>

#define N_NODES 50000
#define N_EDGES 1600000
#define CH 512
#define M_PAD 50048                // 391 * 128
#define SCAN_B 196                 // ceil(50000/256)

typedef float f32x4 __attribute__((ext_vector_type(4)));
typedef unsigned short ushort8v __attribute__((ext_vector_type(8)));
typedef _Float16 half8v __attribute__((ext_vector_type(8)));

#define GLOAD_LDS16(gptr, lptr)                                                        \
    __builtin_amdgcn_global_load_lds((const __attribute__((address_space(1))) void*)(gptr), \
                                     (__attribute__((address_space(3))) void*)(lptr), 16, 0, 0)

__device__ inline unsigned short f2h(float x) {
    union { _Float16 h; unsigned short u; } cv;
    cv.h = (_Float16)x;   // v_cvt_f16_f32, RNE
    return cv.u;
}
__device__ inline float h2f(unsigned short u) {
    union { unsigned short u; _Float16 h; } cv;
    cv.u = u;
    return (float)cv.h;
}

// ---------------- edge bucketing (counting sort by row) ----------------

__global__ __launch_bounds__(256) void hist_kernel(const int* __restrict__ row,
                                                   int* __restrict__ counts) {
    int e = blockIdx.x * 256 + threadIdx.x;
    if (e < N_EDGES) atomicAdd(&counts[row[e]], 1);
}

__global__ __launch_bounds__(256) void bsum_kernel(const int* __restrict__ counts,
                                                   int* __restrict__ bsum) {
    __shared__ int red[256];
    int i = blockIdx.x * 256 + threadIdx.x;
    red[threadIdx.x] = (i < N_NODES) ? counts[i] : 0;
    __syncthreads();
    for (int s = 128; s > 0; s >>= 1) {
        if (threadIdx.x < s) red[threadIdx.x] += red[threadIdx.x + s];
        __syncthreads();
    }
    if (threadIdx.x == 0) bsum[blockIdx.x] = red[0];
}

__global__ __launch_bounds__(256) void bscan_kernel(const int* __restrict__ bsum,
                                                    int* __restrict__ bbase) {
    __shared__ int sc[256];
    int t = threadIdx.x;
    int v = (t < SCAN_B) ? bsum[t] : 0;
    sc[t] = v;
    __syncthreads();
    for (int d = 1; d < 256; d <<= 1) {
        int a = (t >= d) ? sc[t - d] : 0;
        __syncthreads();
        sc[t] += a;
        __syncthreads();
    }
    if (t < SCAN_B) bbase[t] = sc[t] - v;  // exclusive
}

__global__ __launch_bounds__(256) void offsets_kernel(const int* __restrict__ counts,
                                                      const int* __restrict__ bbase,
                                                      int* __restrict__ offsets,
                                                      int* __restrict__ nxt) {
    __shared__ int sc[256];
    int t = threadIdx.x;
    int i = blockIdx.x * 256 + t;
    int v = (i < N_NODES) ? counts[i] : 0;
    sc[t] = v;
    __syncthreads();
    for (int d = 1; d < 256; d <<= 1) {
        int a = (t >= d) ? sc[t - d] : 0;
        __syncthreads();
        sc[t] += a;
        __syncthreads();
    }
    int off = bbase[blockIdx.x] + sc[t] - v;
    if (i < N_NODES) { offsets[i] = off; nxt[i] = off; }
    if (i == 0) offsets[N_NODES] = N_EDGES;
}

__global__ __launch_bounds__(256) void scatter_kernel(const int* __restrict__ row,
                                                      const int* __restrict__ col,
                                                      const float* __restrict__ val,
                                                      int* __restrict__ nxt,
                                                      int2* __restrict__ ep) {
    int e = blockIdx.x * 256 + threadIdx.x;
    if (e < N_EDGES) {
        int r = row[e];
        int p = atomicAdd(&nxt[r], 1);
        ep[p] = make_int2(col[e], __float_as_int(val[e]));
    }
}

// ---------------- X pre-convert: Xa[kt][m][32] fp16 (plain slot order) ----------------

__global__ __launch_bounds__(256) void prep_x(const float* __restrict__ X,
                                              unsigned short* __restrict__ Xa) {
    const int t = threadIdx.x;
    const int m = blockIdx.x * 32 + (t >> 3);
    const int cpart = t & 7;  // 64-ch chunk -> kts cpart*2, cpart*2+1
    float xv[64];
    if (m < N_NODES) {
        const float* xp = &X[(size_t)m * CH + cpart * 64];
#pragma unroll
        for (int i = 0; i < 16; ++i)
            *(float4*)&xv[i * 4] = *(const float4*)&xp[i * 4];
    } else {
#pragma unroll
        for (int i = 0; i < 64; ++i) xv[i] = 0.f;
    }
#pragma unroll
    for (int kk = 0; kk < 2; ++kk) {
        const int kt = cpart * 2 + kk;
        ushort8v o[4];
#pragma unroll
        for (int q = 0; q < 32; ++q)
            o[q >> 3][q & 7] = f2h(xv[kk * 32 + q]);
        unsigned short* dst = &Xa[((size_t)kt * M_PAD + m) * 32];
        *(ushort8v*)&dst[0]  = o[0];
        *(ushort8v*)&dst[8]  = o[1];
        *(ushort8v*)&dst[16] = o[2];
        *(ushort8v*)&dst[24] = o[3];
    }
}

// ---------------- W pre-transform: Wb[kt][n][64] fp16 (hi k0..31 | lo k0..31) ----------------

__global__ __launch_bounds__(256) void prep_w(const float* __restrict__ W,
                                              unsigned short* __restrict__ Wb) {
    __shared__ float tile[32][65];
    const int kt = blockIdx.x;       // 16 K-tiles of 32
    const int nb = blockIdx.y * 64;  // 8 col groups of 64
    const int t = threadIdx.x;
    const int nl = t & 63, kl = t >> 6;
#pragma unroll
    for (int p = 0; p < 8; ++p) {
        int k = p * 4 + kl;
        tile[k][nl] = W[(size_t)(kt * 32 + k) * CH + nb + nl];
    }
    __syncthreads();
    const int n_local = t >> 2, j = t & 3;
    ushort8v hi, lo;
#pragma unroll
    for (int q = 0; q < 8; ++q) {
        float x = tile[j * 8 + q][n_local];
        unsigned short h = f2h(x);
        hi[q] = h;
        lo[q] = f2h(x - h2f(h));
    }
    size_t base = ((size_t)kt * 512 + nb + n_local) * 64 + j * 8;
    *(ushort8v*)&Wb[base] = hi;       // hi slot j
    *(ushort8v*)&Wb[base + 32] = lo;  // lo slot 4+j
}

// ---------------- GEMM: support(fp16) = Xa @ (Whi + Wlo), 2-phase pipelined ----------------
// BM=BN=128, BK=32, 256 threads (4 waves 2x2). Double-buffered LDS; raw s_barrier +
// counted s_waitcnt so prefetched global_load_lds stay in flight across the barrier.

__global__ __launch_bounds__(256) void gemm_kernel(const unsigned short* __restrict__ Xa,
                                                   const unsigned short* __restrict__ Wb,
                                                   unsigned short* __restrict__ S) {
    __shared__ __align__(16) unsigned short Al[2][128 * 32];
    __shared__ __align__(16) unsigned short Bl[2][128 * 64];

    const int tid = threadIdx.x;
    const int wave = tid >> 6;
    const int lane = tid & 63;
    const int wm = (wave >> 1) * 64;
    const int wn = (wave & 1) * 64;
    const int m0 = blockIdx.x * 128;
    const int n0 = blockIdx.y * 128;

    // staging lane offsets (pre-swizzled global source, linear LDS dest)
    const int lrow = lane >> 3, lslot = lane & 7;
    const int b_lane_off = lrow * 64 + ((lslot ^ lrow) << 3);
    const int arow_l = lane >> 2, aslot = lane & 3;
    const int a_lane_off = arow_l * 32 + ((aslot ^ (arow_l & 3)) << 3);

    const unsigned short* bsrc0 = Wb + ((size_t)(n0 + wave * 32)) * 64 + b_lane_off;
    const unsigned short* asrc0 = Xa + ((size_t)(m0 + wave * 16)) * 32 + a_lane_off;

    const int fr = lane & 15;
    const int fs = lane >> 4;
    const int fx3 = fr & 3;
    const int fx7 = fr & 7;

    f32x4 acc[4][4] = {};

    // prologue: stage tile 0 into buffer 0
    {
        const unsigned short* bsrc = bsrc0;
        unsigned short* bdst = &Bl[0][(wave * 32) * 64];
        GLOAD_LDS16(bsrc, bdst);
        GLOAD_LDS16(bsrc + 512, bdst + 512);
        GLOAD_LDS16(bsrc + 1024, bdst + 1024);
        GLOAD_LDS16(bsrc + 1536, bdst + 1536);
        const unsigned short* asrc = asrc0;
        unsigned short* adst = &Al[0][(wave * 16) * 32];
        GLOAD_LDS16(asrc, adst);
        GLOAD_LDS16(asrc + 64 * 32, adst + 64 * 32);
    }

#pragma unroll
    for (int kt = 0; kt < 16; ++kt) {
        const int cur = kt & 1;
        // tile kt's loads (issued last iter / prologue) complete; sync all waves
        asm volatile("s_waitcnt vmcnt(0)" ::: "memory");
        __builtin_amdgcn_s_barrier();

        // issue next tile's loads into the other buffer (they fly across this iter)
        if (kt < 15) {
            const unsigned short* bsrc = bsrc0 + (size_t)(kt + 1) * (512 * 64);
            unsigned short* bdst = &Bl[cur ^ 1][(wave * 32) * 64];
            GLOAD_LDS16(bsrc, bdst);
            GLOAD_LDS16(bsrc + 512, bdst + 512);
            GLOAD_LDS16(bsrc + 1024, bdst + 1024);
            GLOAD_LDS16(bsrc + 1536, bdst + 1536);
            const unsigned short* asrc = asrc0 + (size_t)(kt + 1) * ((size_t)M_PAD * 32);
            unsigned short* adst = &Al[cur ^ 1][(wave * 16) * 32];
            GLOAD_LDS16(asrc, adst);
            GLOAD_LDS16(asrc + 64 * 32, adst + 64 * 32);
        }

        // read all fragments of tile kt
        half8v af[4], bh[4], bl[4];
#pragma unroll
        for (int mi = 0; mi < 4; ++mi)
            af[mi] = *(const half8v*)&Al[cur][(wm + mi * 16 + fr) * 32 + ((fs ^ fx3) << 3)];
#pragma unroll
        for (int ni = 0; ni < 4; ++ni) {
            const unsigned short* br = &Bl[cur][(wn + ni * 16 + fr) * 64];
            bh[ni] = *(const half8v*)&br[((fs ^ fx7) << 3)];
            bl[ni] = *(const half8v*)&br[(((fs | 4) ^ fx7) << 3)];
        }
        // all waves done reading buf[cur] -> safe to overwrite next iter
        asm volatile("s_waitcnt lgkmcnt(0)" ::: "memory");
        __builtin_amdgcn_sched_barrier(0);
        __builtin_amdgcn_s_barrier();

        // 32 MFMA (register-only)
#pragma unroll
        for (int ni = 0; ni < 4; ++ni)
#pragma unroll
            for (int mi = 0; mi < 4; ++mi) {
                acc[mi][ni] = __builtin_amdgcn_mfma_f32_16x16x32_f16(af[mi], bh[ni], acc[mi][ni], 0, 0, 0);
                acc[mi][ni] = __builtin_amdgcn_mfma_f32_16x16x32_f16(af[mi], bl[ni], acc[mi][ni], 0, 0, 0);
            }
    }

    // ---- store C as fp16: col = lane&15, row = (lane>>4)*4 + reg ----
    const int crow = (lane >> 4) * 4;
    const int ccol = lane & 15;
#pragma unroll
    for (int mi = 0; mi < 4; ++mi) {
#pragma unroll
        for (int r = 0; r < 4; ++r) {
            int gm = m0 + wm + mi * 16 + crow + r;
            if (gm < N_NODES) {
#pragma unroll
                for (int ni = 0; ni < 4; ++ni) {
                    S[(size_t)gm * CH + n0 + wn + ni * 16 + ccol] = f2h(acc[mi][ni][r]);
                }
            }
        }
    }
}

// ---------------- SpMM: out[r] = sum_e val_e * support[col_e] ----------------
// one wave per row; lane covers 8 channels (half8 = 16B/lane); 8x edge unroll.

__global__ __launch_bounds__(128) void spmm_kernel(const int* __restrict__ offsets,
                                                   const int2* __restrict__ ep,
                                                   const unsigned short* __restrict__ S,
                                                   float* __restrict__ out) {
    const int r = blockIdx.x * 2 + (threadIdx.x >> 6);
    const int lane = threadIdx.x & 63;
    const int c = lane * 8;
    const int start = offsets[r];
    const int end = offsets[r + 1];

    float acc[8] = {0.f, 0.f, 0.f, 0.f, 0.f, 0.f, 0.f, 0.f};
    int e = start;
    for (; e + 7 < end; e += 8) {
        int2 ee[8];
#pragma unroll
        for (int u = 0; u < 8; ++u) ee[u] = ep[e + u];
        half8v sv[8];
#pragma unroll
        for (int u = 0; u < 8; ++u)
            sv[u] = *(const half8v*)&S[(size_t)ee[u].x * CH + c];
#pragma unroll
        for (int u = 0; u < 8; ++u) {
            const float v = __int_as_float(ee[u].y);
#pragma unroll
            for (int j = 0; j < 8; ++j) acc[j] += v * (float)sv[u][j];
        }
    }
    for (; e < end; ++e) {
        const int2 e0 = ep[e];
        const half8v s0 = *(const half8v*)&S[(size_t)e0.x * CH + c];
        const float v0 = __int_as_float(e0.y);
#pragma unroll
        for (int j = 0; j < 8; ++j) acc[j] += v0 * (float)s0[j];
    }
    float4 o0 = {acc[0], acc[1], acc[2], acc[3]};
    float4 o1 = {acc[4], acc[5], acc[6], acc[7]};
    *(float4*)&out[(size_t)r * CH + c] = o0;
    *(float4*)&out[(size_t)r * CH + c + 4] = o1;
}

// ---------------- launch ----------------

extern "C" void kernel_launch(void* const* d_in, const int* in_sizes, int n_in,
                              void* d_out, int out_size, void* d_ws, size_t ws_size,
                              hipStream_t stream) {
    const float* x        = (const float*)d_in[0];
    const float* adj_vals = (const float*)d_in[1];
    const int*   edge_row = (const int*)d_in[2];
    const int*   edge_col = (const int*)d_in[3];
    const float* weight   = (const float*)d_in[4];
    float* out = (float*)d_out;

    auto align256 = [](size_t v) { return (v + 255) & ~(size_t)255; };
    char* ws = (char*)d_ws;
    size_t off = 0;
    unsigned short* support = (unsigned short*)(ws + off); off = align256(off + (size_t)N_NODES * CH * sizeof(unsigned short));
    unsigned short* Xa = (unsigned short*)(ws + off);      off = align256(off + (size_t)16 * M_PAD * 32 * sizeof(unsigned short));
    int*   counts  = (int*)(ws + off);            off = align256(off + (size_t)N_NODES * sizeof(int));
    int*   offsets = (int*)(ws + off);            off = align256(off + (size_t)(N_NODES + 1) * sizeof(int));
    int*   nxt     = (int*)(ws + off);            off = align256(off + (size_t)N_NODES * sizeof(int));
    int2*  ep      = (int2*)(ws + off);           off = align256(off + (size_t)N_EDGES * sizeof(int2));
    unsigned short* Wb = (unsigned short*)(ws + off); off = align256(off + (size_t)16 * 512 * 64 * sizeof(unsigned short));
    int*   bsum    = (int*)(ws + off);            off = align256(off + (size_t)SCAN_B * sizeof(int));
    int*   bbase   = (int*)(ws + off);            off = align256(off + (size_t)SCAN_B * sizeof(int));

    (void)hipMemsetAsync(counts, 0, (size_t)N_NODES * sizeof(int), stream);

    const int EB = (N_EDGES + 255) / 256;
    hist_kernel<<<EB, 256, 0, stream>>>(edge_row, counts);
    bsum_kernel<<<SCAN_B, 256, 0, stream>>>(counts, bsum);
    bscan_kernel<<<1, 256, 0, stream>>>(bsum, bbase);
    offsets_kernel<<<SCAN_B, 256, 0, stream>>>(counts, bbase, offsets, nxt);
    scatter_kernel<<<EB, 256, 0, stream>>>(edge_row, edge_col, adj_vals, nxt, ep);

    prep_x<<<M_PAD / 32, 256, 0, stream>>>(x, Xa);
    dim3 wgrid(16, 8);
    prep_w<<<wgrid, 256, 0, stream>>>(weight, Wb);

    dim3 ggrid(M_PAD / 128, CH / 128);
    gemm_kernel<<<ggrid, 256, 0, stream>>>(Xa, Wb, support);

    spmm_kernel<<<N_NODES / 2, 128, 0, stream>>>(offsets, ep, support, out);
}